// Round 1
// baseline (154.564 us; speedup 1.0000x reference)
//
#include <hip/hip_runtime.h>

// RuleClassifierSNN — forward only.
// Key algebraic facts (see analysis):
//  * spike(post-reset v) == 0 always  -> W_rec terms vanish in forward.
//  * layer-0 drive is a V=128 entry lookup table:
//      table0[v] = 0.2f * ((emb[v] @ W_in.T + b_in) @ W_lif0.T + b_lif0)
//  * only real GEMM: s0[t] @ (0.2f*W_lif1).T, s0 binary {0,1} (exact in bf16).
//    W split hi/lo bf16 -> ~2^-16 relative accuracy via two fp32-accum MFMAs.

#define T_STEPS 256
#define B_SZ    2048
#define H_SZ    128
#define V_SZ    128
#define E_SZ    64
#define C_SZ    12

typedef __attribute__((ext_vector_type(8))) short bf16x8;
typedef __attribute__((ext_vector_type(4))) float f32x4;

static __device__ __forceinline__ short f2bf(float f) {
  unsigned u = __float_as_uint(f);
  u = (u + 0x7FFFu + ((u >> 16) & 1u)) >> 16;   // RNE; inputs never NaN
  return (short)u;
}
static __device__ __forceinline__ float bf2f(short b) {
  return __uint_as_float(((unsigned)(unsigned short)b) << 16);
}

// (1.0 - 0.8) computed in double then cast to f32, matching JAX's weak-typed
// scalar: rounds to 0x3E4CCCCD == 0.2f.
#define OMB 0.2f
#define BETA 0.8f

// ---------------------------------------------------------------------------
// Kernel 1: build the layer-0 lookup table. 128 blocks (one per vocab id) x 128.
__global__ void k_table(const float* __restrict__ emb, const float* __restrict__ W_in,
                        const float* __restrict__ b_in, const float* __restrict__ W_lif0,
                        const float* __restrict__ b_lif0, float* __restrict__ table0p) {
  __shared__ float x1s[H_SZ];
  int v = blockIdx.x, h = threadIdx.x;
  float s = b_in[h];
  const float* er = emb + v * E_SZ;
  const float* wr = W_in + h * E_SZ;
#pragma unroll 8
  for (int e = 0; e < E_SZ; ++e) s += er[e] * wr[e];
  x1s[h] = s;
  __syncthreads();
  float t0 = b_lif0[h];
  const float* w0 = W_lif0 + h * H_SZ;
#pragma unroll 8
  for (int i = 0; i < H_SZ; ++i) t0 += x1s[i] * w0[i];
  table0p[v * H_SZ + h] = OMB * t0;
}

// ---------------------------------------------------------------------------
// Kernel 2: layer-0 LIF scan, one thread per (b,h) chain; emits s0 spikes as
// bf16 {0,1} into an MFMA-A-fragment swizzled layout:
//   elem(t,b,h) = t*B*H + (b>>4)*2048 + (h>>5)*512
//               + (((h>>3)&3)*16 + (b&15))*8 + (h&7)
// Lane mapping chosen so each wave's 64 stores are 128 consecutive bytes.
__global__ void k_layer0(const int* __restrict__ ids, const float* __restrict__ table0p,
                         unsigned short* __restrict__ s0s) {
  int u = blockIdx.x * blockDim.x + threadIdx.x;   // [0, 262144)
  int lane = u & 63;
  int hl = lane & 7;          // h & 7
  int bl = (lane >> 3) & 7;   // b & 7
  int w  = u >> 6;
  int b = (w >> 4) * 8 + bl;  // [0, 2048)
  int h = (w & 15) * 8 + hl;  // [0, 128)
  const int* idrow = ids + b * T_STEPS;
  int base = (b >> 4) * 2048 + (h >> 5) * 512 + (((h >> 3) & 3) * 16 + (b & 15)) * 8 + (h & 7);
  float v = 0.0f;
  for (int t = 0; t < T_STEPS; ++t) {
    float tv = table0p[idrow[t] * H_SZ + h];
    v = fmaf(BETA, v, tv);
    bool sp = v >= 1.0f;
    s0s[(long)t * (B_SZ * H_SZ) + base] = sp ? (unsigned short)0x3F80 : (unsigned short)0;
    if (sp) v = 0.0f;
  }
}

// ---------------------------------------------------------------------------
// Kernel 3: layer-1 scan. 256 blocks (1/CU) x 4 waves. Wave = 16b x 16h tile,
// K=128. W (0.2f*W_lif1) lives in registers as bf16 hi/lo fragments; v1 and
// spike-count acc live in MFMA C-layout registers for all 256 steps.
__device__ __forceinline__ void scan_body(const bf16x8* A, const bf16x8* Whi,
                                          const bf16x8* Wlo, float b1v,
                                          f32x4& v1, f32x4& acc) {
  f32x4 Chi = {b1v, b1v, b1v, b1v};
  f32x4 Clo = {0.f, 0.f, 0.f, 0.f};
#pragma unroll
  for (int kt = 0; kt < 4; ++kt)
    Chi = __builtin_amdgcn_mfma_f32_16x16x32_bf16(A[kt], Whi[kt], Chi, 0, 0, 0);
#pragma unroll
  for (int kt = 0; kt < 4; ++kt)
    Clo = __builtin_amdgcn_mfma_f32_16x16x32_bf16(A[kt], Wlo[kt], Clo, 0, 0, 0);
#pragma unroll
  for (int r = 0; r < 4; ++r) {
    float cur = Chi[r] + Clo[r];
    float nv  = fmaf(BETA, v1[r], cur);
    bool sp   = nv >= 1.0f;
    acc[r] += sp ? 1.0f : 0.0f;
    v1[r]   = sp ? 0.0f : nv;
  }
}

__launch_bounds__(256, 1)
__global__ void k_scan(const unsigned short* __restrict__ s0s,
                       const float* __restrict__ W1, const float* __restrict__ b_lif,
                       float* __restrict__ accbuf) {
  int bid = blockIdx.x;
  // swizzle so the two blocks sharing a btile (n-halves) land on the same XCD
  int btile = (bid & 7) * 16 + (bid >> 4);   // [0,128)
  int nhalf = (bid >> 3) & 1;
  int wid  = threadIdx.x >> 6;
  int lane = threadIdx.x & 63;
  int nl = lane & 15, quad = lane >> 4;
  int h0 = nhalf * 64 + wid * 16;
  int n  = h0 + nl;                           // output h == W row

  // Register-resident W fragments (hi/lo bf16 split of 0.2f*W_lif1)
  bf16x8 Whi[4], Wlo[4];
  const float* wrow = W1 + n * H_SZ;
#pragma unroll
  for (int kt = 0; kt < 4; ++kt) {
    const float* wp = wrow + kt * 32 + quad * 8;
    bf16x8 hi, lo;
#pragma unroll
    for (int j = 0; j < 8; ++j) {
      float ws = OMB * wp[j];
      short hb = f2bf(ws);
      hi[j] = hb;
      lo[j] = f2bf(ws - bf2f(hb));
    }
    Whi[kt] = hi; Wlo[kt] = lo;
  }
  float b1v = OMB * b_lif[H_SZ + n];

  const bf16x8* As = (const bf16x8*)s0s;
  const long tstride = 32768;                 // 128 btiles * 4 kt * 64 lanes
  long fbase = (long)btile * 256 + lane;

  f32x4 v1  = {0.f, 0.f, 0.f, 0.f};
  f32x4 acc = {0.f, 0.f, 0.f, 0.f};

  bf16x8 A[4][4];                              // depth-4 prefetch ring
#pragma unroll
  for (int s = 0; s < 4; ++s)
#pragma unroll
    for (int kt = 0; kt < 4; ++kt) A[s][kt] = As[(long)s * tstride + fbase + kt * 64];

  for (int t = 0; t < T_STEPS; t += 4) {
#pragma unroll
    for (int s = 0; s < 4; ++s) {
      scan_body(A[s], Whi, Wlo, b1v, v1, acc);
      int tn = t + 4 + s;
      if (tn < T_STEPS) {
#pragma unroll
        for (int kt = 0; kt < 4; ++kt) A[s][kt] = As[(long)tn * tstride + fbase + kt * 64];
      }
    }
  }
#pragma unroll
  for (int r = 0; r < 4; ++r) {
    int b = btile * 16 + quad * 4 + r;
    accbuf[b * H_SZ + n] = acc[r];
  }
}

// ---------------------------------------------------------------------------
// Kernel 4: logits = (acc/256) @ W_cls.T + b_cls
__global__ void k_logits(const float* __restrict__ accbuf, const float* __restrict__ Wc,
                         const float* __restrict__ bc, float* __restrict__ out) {
  int u = blockIdx.x * blockDim.x + threadIdx.x;
  if (u >= B_SZ * C_SZ) return;
  int b = u / C_SZ, c = u - b * C_SZ;
  const float4* a4 = (const float4*)(accbuf + b * H_SZ);
  const float4* w4 = (const float4*)(Wc + c * H_SZ);
  float s = bc[c];
#pragma unroll
  for (int i = 0; i < H_SZ / 4; ++i) {
    float4 a = a4[i], wv = w4[i];
    s += (a.x * 0.00390625f) * wv.x + (a.y * 0.00390625f) * wv.y +
         (a.z * 0.00390625f) * wv.z + (a.w * 0.00390625f) * wv.w;
  }
  out[u] = s;
}

// ---------------------------------------------------------------------------
extern "C" void kernel_launch(void* const* d_in, const int* in_sizes, int n_in,
                              void* d_out, int out_size, void* d_ws, size_t ws_size,
                              hipStream_t stream) {
  (void)in_sizes; (void)n_in; (void)out_size; (void)ws_size;
  const int*   ids   = (const int*)d_in[0];
  const float* emb   = (const float*)d_in[1];
  const float* W_in  = (const float*)d_in[2];
  const float* b_in  = (const float*)d_in[3];
  const float* W_lif = (const float*)d_in[4];
  const float* b_lif = (const float*)d_in[5];
  // d_in[6] (W_rec) provably unused in forward
  const float* W_cls = (const float*)d_in[7];
  const float* b_cls = (const float*)d_in[8];
  float* out = (float*)d_out;

  char* ws = (char*)d_ws;
  unsigned short* s0s = (unsigned short*)ws;                      // 134,217,728 B
  float* table0p = (float*)(ws + 134217728);                      //      65,536 B
  float* accbuf  = (float*)(ws + 134217728 + 65536);              //   1,048,576 B

  k_table <<<V_SZ, H_SZ, 0, stream>>>(emb, W_in, b_in, W_lif, b_lif, table0p);
  k_layer0<<<(B_SZ * H_SZ) / 256, 256, 0, stream>>>(ids, table0p, s0s);
  k_scan  <<<256, 256, 0, stream>>>(s0s, W_lif + H_SZ * H_SZ, b_lif, accbuf);
  k_logits<<<(B_SZ * C_SZ + 255) / 256, 256, 0, stream>>>(accbuf, W_cls, b_cls, out);
}